// Round 7
// baseline (258.578 us; speedup 1.0000x reference)
//
#include <hip/hip_runtime.h>
#include <math.h>

#define N_NODES 60000
#define N_EDGES 240000
#define F_INQ 10
#define G_DIM 512
#define NB_SCAN ((N_NODES + 255) / 256)   // 235
#define NB_EDGE ((N_EDGES + 255) / 256)   // 938

// ===========================================================================
// K_prep: fused degree histogram (blocks [0,NB_EDGE)) + graph-segment table
// (blocks [NB_EDGE, NB_EDGE+NB_SCAN)).
// ===========================================================================
__global__ __launch_bounds__(256) void k_prep(
    const int* __restrict__ ei, int* __restrict__ rs,
    const int* __restrict__ seg, int* __restrict__ gs)
{
    if (blockIdx.x < NB_EDGE) {
        int e = blockIdx.x * 256 + threadIdx.x;
        if (e < N_EDGES) atomicAdd(&rs[ei[e]], 1);
    } else {
        int i = (blockIdx.x - NB_EDGE) * 256 + threadIdx.x;
        if (i >= N_NODES) return;
        int s = seg[i];
        if (i == 0) { for (int g = 0; g <= s; ++g) gs[g] = 0; }
        else {
            int pr = seg[i - 1];
            for (int g = pr + 1; g <= s; ++g) gs[g] = i;
        }
        if (i == N_NODES - 1) { for (int g = s + 1; g <= G_DIM; ++g) gs[g] = N_NODES; }
    }
}

// ===========================================================================
// K_scan: per-block exclusive scan of rs + block totals; last block (ticket)
// exclusive-scans bsum in place. Global offset = rs[i] + bsum[i>>8].
// ===========================================================================
__global__ __launch_bounds__(256) void k_scan(
    int* __restrict__ rs, int* __restrict__ bsum, int* __restrict__ cnt)
{
    __shared__ int s[256];
    __shared__ int amLast;
    int i = blockIdx.x * 256 + threadIdx.x;
    int v = (i < N_NODES) ? rs[i] : 0;
    s[threadIdx.x] = v;
    __syncthreads();
    for (int off = 1; off < 256; off <<= 1) {
        int t = (threadIdx.x >= off) ? s[threadIdx.x - off] : 0;
        __syncthreads();
        s[threadIdx.x] += t;
        __syncthreads();
    }
    if (i < N_NODES) rs[i] = s[threadIdx.x] - v;  // block-local exclusive
    __syncthreads();
    if (threadIdx.x == 0) {
        bsum[blockIdx.x] = s[255];
        __threadfence();
        amLast = (atomicAdd(cnt, 1) == (int)gridDim.x - 1);
    }
    __syncthreads();
    if (!amLast) return;
    __threadfence();
    int b = (threadIdx.x < NB_SCAN) ? bsum[threadIdx.x] : 0;
    s[threadIdx.x] = b;
    __syncthreads();
    for (int off = 1; off < 256; off <<= 1) {
        int t = (threadIdx.x >= off) ? s[threadIdx.x - off] : 0;
        __syncthreads();
        s[threadIdx.x] += t;
        __syncthreads();
    }
    if (threadIdx.x < NB_SCAN) bsum[threadIdx.x] = s[threadIdx.x] - b;
}

__global__ __launch_bounds__(256) void k_fill(
    const int* __restrict__ ei, const float* __restrict__ a_vals,
    const float* __restrict__ efeat,
    int* __restrict__ rs, const int* __restrict__ bsum,
    int* __restrict__ ecol, float4* __restrict__ edata)
{
    int e = blockIdx.x * 256 + threadIdx.x;
    if (e >= N_EDGES) return;
    int row = ei[e];
    int slot = atomicAdd(&rs[row], 1) + bsum[row >> 8];
    ecol[slot] = ei[N_EDGES + e];
    edata[slot] = make_float4(a_vals[e], efeat[e * 3], efeat[e * 3 + 1], efeat[e * 3 + 2]);
}

// ---------------------------------------------------------------------------
// K_edgetf1: fused layer 1. Block = 16 nodes, 16 lanes/node.
// Edge phase (lane f<10): weight-free CSR reduction into registers; PQ and
// x-self parked in LDS (padded strides 51/11 -> conflict-free). Then tf phase
// (lane o<16) applies all weights from LDS: one pass, no PQ1 global array.
// Output interleaved g1c1[n*32+2o] = (g1, c1) float2.
// ---------------------------------------------------------------------------
__global__ __launch_bounds__(256) void k_edgetf1(
    const float* __restrict__ x,
    const int* __restrict__ rs, const int* __restrict__ bsum,
    const int* __restrict__ ecol, const float4* __restrict__ edata,
    const float* __restrict__ Wg1,   // [10,16]
    const float* __restrict__ We1,   // [3,160]
    const float* __restrict__ be1,   // [160]
    const float* __restrict__ root1, // [10,16]
    const float* __restrict__ bias1, // [16]
    const float* __restrict__ bg1,   // [16]
    float* __restrict__ g1c1)
{
    __shared__ float w[6 * 160 + 32];   // wg|w0|w1|w2|bm|rt | bias1 | bg1
    __shared__ float pq[16][51];
    __shared__ float xs[16][11];
    for (int t = threadIdx.x; t < 6 * 160 + 32; t += 256) {
        float v;
        if (t < 960) {
            int slot = t / 160, r = t - slot * 160;
            if (slot == 0)      v = Wg1[r];
            else if (slot <= 3) v = We1[(slot - 1) * 160 + r];
            else if (slot == 4) v = be1[r];
            else                v = root1[r];
        } else if (t < 976) v = bias1[t - 960];
        else                v = bg1[t - 976];
        w[t] = v;
    }
    int n = threadIdx.x >> 4, f = threadIdx.x & 15;
    int node = blockIdx.x * 16 + n;     // 3750 blocks exact
    int end = rs[node] + bsum[node >> 8];
    int start = (node == 0) ? 0 : (rs[node - 1] + bsum[(node - 1) >> 8]);
    if (f < F_INQ) {
        float p0 = 0.f, p1 = 0.f, p2 = 0.f, p3 = 0.f, q = 0.f;
        for (int k = start; k < end; ++k) {
            int col = ecol[k];
            float4 ed = edata[k];
            float xv = x[col * F_INQ + f];
            p0 += xv;
            p1 += ed.y * xv;
            p2 += ed.z * xv;
            p3 += ed.w * xv;
            q  += ed.x * xv;
        }
        pq[n][f]      = p0;
        pq[n][10 + f] = p1;
        pq[n][20 + f] = p2;
        pq[n][30 + f] = p3;
        pq[n][40 + f] = q;
        xs[n][f] = x[node * F_INQ + f];
    }
    __syncthreads();
    int o = f;
    float ac = w[960 + o], ag = w[976 + o];
#pragma unroll
    for (int ff = 0; ff < 10; ++ff) {
        ac += pq[n][ff] * w[640 + ff * 16 + o]
            + pq[n][10 + ff] * w[160 + ff * 16 + o]
            + pq[n][20 + ff] * w[320 + ff * 16 + o]
            + pq[n][30 + ff] * w[480 + ff * 16 + o]
            + xs[n][ff] * w[800 + ff * 16 + o];
        ag += pq[n][40 + ff] * w[ff * 16 + o];
    }
    float2 gc;
    gc.x = ag > 0.f ? ag : 0.f;
    gc.y = ac > 0.f ? ac : 0.f;
    *reinterpret_cast<float2*>(g1c1 + node * 32 + 2 * o) = gc;
}

// ---------------------------------------------------------------------------
// K_edgetf2: fused layer 2. Block = 16 nodes, 16 lanes/node in edge phase
// (one float2 gather/edge/lane from interleaved g1c1); PQ in LDS [16][81]
// (81 mod 32 = 17, odd -> conflict-free). tf phase remaps to (8 nodes x 32 o)
// and runs twice. Output g2c2[n,64] = [g2(32)|c2(32)]. No PQ2 global array.
// ---------------------------------------------------------------------------
__global__ __launch_bounds__(256) void k_edgetf2(
    const float* __restrict__ g1c1,
    const int* __restrict__ rs, const int* __restrict__ bsum,
    const int* __restrict__ ecol, const float4* __restrict__ edata,
    const float* __restrict__ Wg2,   // [16,32]
    const float* __restrict__ We2,   // [3,512]
    const float* __restrict__ be2,   // [512]
    const float* __restrict__ root2, // [16,32]
    const float* __restrict__ bias2, // [32]
    const float* __restrict__ bg2,   // [32]
    float* __restrict__ g2c2)
{
    __shared__ float w[6 * 512 + 64];   // wg|w0|w1|w2|bm|rt | bias2 | bg2
    __shared__ float pq[16][81];
    __shared__ float cs[16][17];
    for (int t = threadIdx.x; t < 6 * 512 + 64; t += 256) {
        float v;
        if (t < 3072) {
            int slot = t >> 9, r = t & 511;
            if (slot == 0)      v = Wg2[r];
            else if (slot <= 3) v = We2[(slot - 1) * 512 + r];
            else if (slot == 4) v = be2[r];
            else                v = root2[r];
        } else if (t < 3104) v = bias2[t - 3072];
        else                 v = bg2[t - 3104];
        w[t] = v;
    }
    int n = threadIdx.x >> 4, f = threadIdx.x & 15;
    int node = blockIdx.x * 16 + n;     // 3750 blocks exact
    int end = rs[node] + bsum[node >> 8];
    int start = (node == 0) ? 0 : (rs[node - 1] + bsum[(node - 1) >> 8]);
    float p0 = 0.f, p1 = 0.f, p2 = 0.f, p3 = 0.f, q = 0.f;
    for (int k = start; k < end; ++k) {
        int col = ecol[k];
        float4 ed = edata[k];
        float2 gcv = *reinterpret_cast<const float2*>(g1c1 + col * 32 + 2 * f);
        p0 += gcv.y;
        p1 += ed.y * gcv.y;
        p2 += ed.z * gcv.y;
        p3 += ed.w * gcv.y;
        q  += ed.x * gcv.x;
    }
    pq[n][f]      = p0;
    pq[n][16 + f] = p1;
    pq[n][32 + f] = p2;
    pq[n][48 + f] = p3;
    pq[n][64 + f] = q;
    cs[n][f] = g1c1[node * 32 + 2 * f + 1];
    __syncthreads();
    int o = threadIdx.x & 31;
    int n2 = threadIdx.x >> 5;          // 0..7
#pragma unroll
    for (int h = 0; h < 2; ++h) {
        int nn = h * 8 + n2;
        int nodeo = blockIdx.x * 16 + nn;
        float ac = w[3072 + o], ag = w[3104 + o];
#pragma unroll
        for (int ff = 0; ff < 16; ++ff) {
            ac += pq[nn][ff] * w[2048 + ff * 32 + o]
                + pq[nn][16 + ff] * w[512 + ff * 32 + o]
                + pq[nn][32 + ff] * w[1024 + ff * 32 + o]
                + pq[nn][48 + ff] * w[1536 + ff * 32 + o]
                + cs[nn][ff] * w[2560 + ff * 32 + o];
            ag += pq[nn][64 + ff] * w[ff * 32 + o];
        }
        g2c2[nodeo * 64 + o]      = ag > 0.f ? ag : 0.f;
        g2c2[nodeo * 64 + 32 + o] = ac > 0.f ? ac : 0.f;
    }
}

// ---------------------------------------------------------------------------
// K_pool_head: one block per graph; 4 waves stride nodes (lane = channel),
// LDS-reduce, fused MLP head.
// ---------------------------------------------------------------------------
__global__ __launch_bounds__(256) void k_pool_head(
    const float* __restrict__ g2c2,
    const int* __restrict__ gs,
    const float* __restrict__ Wd1, const float* __restrict__ bd1,
    const float* __restrict__ Wd2, const float* __restrict__ bd2,
    const float* __restrict__ Wo,  const float* __restrict__ bo,
    float* __restrict__ out)
{
    __shared__ float red[4][64];
    __shared__ float pl[64];
    __shared__ float h1s[16], h2s[8];
    int g = blockIdx.x;
    int s = gs[g], e = gs[g + 1];
    int wv = threadIdx.x >> 6, j = threadIdx.x & 63;
    float acc = 0.f;
    for (int nn = s + wv; nn < e; nn += 4)
        acc += g2c2[nn * 64 + j];
    red[wv][j] = acc;
    __syncthreads();
    if (wv == 0) pl[j] = red[0][j] + red[1][j] + red[2][j] + red[3][j];
    __syncthreads();
    int t = threadIdx.x;
    if (t < 16) {
        float a = bd1[t];
        for (int k = 0; k < 64; ++k) a += pl[k] * Wd1[k * 16 + t];
        h1s[t] = a > 0.f ? a : 0.f;
    }
    __syncthreads();
    if (t < 8) {
        float a = bd2[t];
        for (int k = 0; k < 16; ++k) a += h1s[k] * Wd2[k * 8 + t];
        h2s[t] = a > 0.f ? a : 0.f;
    }
    __syncthreads();
    if (t == 0) {
        float a = bo[0];
        for (int k = 0; k < 8; ++k) a += h2s[k] * Wo[k];
        out[g] = 1.f / (1.f + expf(-a));
    }
}

// ---------------------------------------------------------------------------
// Workspace layout:
//   floats: edata E*float4 | g1c1 N*32 (interleaved) | g2c2 N*64
//   ints  : rs[N] | cnt[1] | bsum[256] | gs[G+1] | ecol[E]
// 7 dispatches total (memset + prep + scan + fill + edgetf1 + edgetf2 + pool).
// ---------------------------------------------------------------------------
extern "C" void kernel_launch(void* const* d_in, const int* in_sizes, int n_in,
                              void* d_out, int out_size, void* d_ws, size_t ws_size,
                              hipStream_t stream)
{
    const float* x      = (const float*)d_in[0];
    const float* a_vals = (const float*)d_in[1];
    const float* efeat  = (const float*)d_in[2];
    const int*   ei     = (const int*)d_in[3];
    const int*   seg    = (const int*)d_in[4];
    const float* Wg1    = (const float*)d_in[5];
    const float* bg1    = (const float*)d_in[6];
    const float* Wg2    = (const float*)d_in[7];
    const float* bg2    = (const float*)d_in[8];
    const float* We1    = (const float*)d_in[9];
    const float* be1    = (const float*)d_in[10];
    const float* root1  = (const float*)d_in[11];
    const float* bias1  = (const float*)d_in[12];
    const float* We2    = (const float*)d_in[13];
    const float* be2    = (const float*)d_in[14];
    const float* root2  = (const float*)d_in[15];
    const float* bias2  = (const float*)d_in[16];
    const float* Wd1    = (const float*)d_in[17];
    const float* bd1    = (const float*)d_in[18];
    const float* Wd2    = (const float*)d_in[19];
    const float* bd2    = (const float*)d_in[20];
    const float* Wo     = (const float*)d_in[21];
    const float* bo     = (const float*)d_in[22];

    float4* edata = (float4*)d_ws;
    float*  g1c1 = (float*)(edata + N_EDGES);
    float*  g2c2 = g1c1 + (size_t)N_NODES * 32;
    int*    rs   = (int*)(g2c2 + (size_t)N_NODES * 64);
    int*    cnt  = rs + N_NODES;
    int*    bsum = cnt + 1;
    int*    gs   = bsum + 256;
    int*    ecol = gs + (G_DIM + 1);
    float*  out  = (float*)d_out;

    hipMemsetAsync(rs, 0, sizeof(int) * (N_NODES + 1), stream);  // rs + cnt

    k_prep<<<NB_EDGE + NB_SCAN, 256, 0, stream>>>(ei, rs, seg, gs);
    k_scan<<<NB_SCAN, 256, 0, stream>>>(rs, bsum, cnt);
    k_fill<<<NB_EDGE, 256, 0, stream>>>(ei, a_vals, efeat, rs, bsum, ecol, edata);

    k_edgetf1<<<N_NODES / 16, 256, 0, stream>>>(
        x, rs, bsum, ecol, edata, Wg1, We1, be1, root1, bias1, bg1, g1c1);
    k_edgetf2<<<N_NODES / 16, 256, 0, stream>>>(
        g1c1, rs, bsum, ecol, edata, Wg2, We2, be2, root2, bias2, bg2, g2c2);

    k_pool_head<<<G_DIM, 256, 0, stream>>>(
        g2c2, gs, Wd1, bd1, Wd2, bd2, Wo, bo, out);
}

// Round 8
// 229.065 us; speedup vs baseline: 1.1288x; 1.1288x over previous
//
#include <hip/hip_runtime.h>
#include <math.h>

#define N_NODES 60000
#define N_EDGES 240000
#define F_INQ 10
#define G_DIM 512
#define NB_SCAN ((N_NODES + 255) / 256)   // 235
#define NB_EDGE ((N_EDGES + 255) / 256)   // 938

// ===========================================================================
// K_prep: fused degree histogram (blocks [0,NB_EDGE)) + graph-segment table
// (blocks [NB_EDGE, NB_EDGE+NB_SCAN)).
// ===========================================================================
__global__ __launch_bounds__(256) void k_prep(
    const int* __restrict__ ei, int* __restrict__ rs,
    const int* __restrict__ seg, int* __restrict__ gs)
{
    if (blockIdx.x < NB_EDGE) {
        int e = blockIdx.x * 256 + threadIdx.x;
        if (e < N_EDGES) atomicAdd(&rs[ei[e]], 1);
    } else {
        int i = (blockIdx.x - NB_EDGE) * 256 + threadIdx.x;
        if (i >= N_NODES) return;
        int s = seg[i];
        if (i == 0) { for (int g = 0; g <= s; ++g) gs[g] = 0; }
        else {
            int pr = seg[i - 1];
            for (int g = pr + 1; g <= s; ++g) gs[g] = i;
        }
        if (i == N_NODES - 1) { for (int g = s + 1; g <= G_DIM; ++g) gs[g] = N_NODES; }
    }
}

// ===========================================================================
// K_scan: per-block exclusive scan of rs + block totals; last block (ticket)
// exclusive-scans bsum in place. Global offset = rs[i] + bsum[i>>8].
// ===========================================================================
__global__ __launch_bounds__(256) void k_scan(
    int* __restrict__ rs, int* __restrict__ bsum, int* __restrict__ cnt)
{
    __shared__ int s[256];
    __shared__ int amLast;
    int i = blockIdx.x * 256 + threadIdx.x;
    int v = (i < N_NODES) ? rs[i] : 0;
    s[threadIdx.x] = v;
    __syncthreads();
    for (int off = 1; off < 256; off <<= 1) {
        int t = (threadIdx.x >= off) ? s[threadIdx.x - off] : 0;
        __syncthreads();
        s[threadIdx.x] += t;
        __syncthreads();
    }
    if (i < N_NODES) rs[i] = s[threadIdx.x] - v;  // block-local exclusive
    __syncthreads();
    if (threadIdx.x == 0) {
        bsum[blockIdx.x] = s[255];
        __threadfence();
        amLast = (atomicAdd(cnt, 1) == (int)gridDim.x - 1);
    }
    __syncthreads();
    if (!amLast) return;
    __threadfence();
    int b = (threadIdx.x < NB_SCAN) ? bsum[threadIdx.x] : 0;
    s[threadIdx.x] = b;
    __syncthreads();
    for (int off = 1; off < 256; off <<= 1) {
        int t = (threadIdx.x >= off) ? s[threadIdx.x - off] : 0;
        __syncthreads();
        s[threadIdx.x] += t;
        __syncthreads();
    }
    if (threadIdx.x < NB_SCAN) bsum[threadIdx.x] = s[threadIdx.x] - b;
}

__global__ __launch_bounds__(256) void k_fill(
    const int* __restrict__ ei, const float* __restrict__ a_vals,
    const float* __restrict__ efeat,
    int* __restrict__ rs, const int* __restrict__ bsum,
    int* __restrict__ ecol, float4* __restrict__ edata)
{
    int e = blockIdx.x * 256 + threadIdx.x;
    if (e >= N_EDGES) return;
    int row = ei[e];
    int slot = atomicAdd(&rs[row], 1) + bsum[row >> 8];
    ecol[slot] = ei[N_EDGES + e];
    edata[slot] = make_float4(a_vals[e], efeat[e * 3], efeat[e * 3 + 1], efeat[e * 3 + 2]);
}

// ---------------------------------------------------------------------------
// K_edge1: weight-free CSR reduction, layer 1. Lane = (node, f<10) PACKED
// (thread = node*10+f, no idle lanes). Simple loop (no prefetch — R6 showed
// explicit pipelining regresses at deg~4). PQ1[n,50] = [P0|P1|P2|P3|Q].
// ---------------------------------------------------------------------------
__global__ __launch_bounds__(256) void k_edge1(
    const float* __restrict__ x,
    const int* __restrict__ rs, const int* __restrict__ bsum,
    const int* __restrict__ ecol, const float4* __restrict__ edata,
    float* __restrict__ PQ1)
{
    int idx = blockIdx.x * 256 + threadIdx.x;
    if (idx >= N_NODES * F_INQ) return;
    int node = idx / F_INQ;               // magic-mul division
    int f = idx - node * F_INQ;
    int end = rs[node] + bsum[node >> 8];
    int start = (node == 0) ? 0 : (rs[node - 1] + bsum[(node - 1) >> 8]);
    float p0 = 0.f, p1 = 0.f, p2 = 0.f, p3 = 0.f, q = 0.f;
    for (int k = start; k < end; ++k) {
        int col = ecol[k];
        float4 ed = edata[k];
        float xv = x[col * F_INQ + f];
        p0 += xv;
        p1 += ed.y * xv;
        p2 += ed.z * xv;
        p3 += ed.w * xv;
        q  += ed.x * xv;
    }
    float* P = PQ1 + node * 50;
    P[f]      = p0;
    P[10 + f] = p1;
    P[20 + f] = p2;
    P[30 + f] = p3;
    P[40 + f] = q;
}

// ---------------------------------------------------------------------------
// K_tf1: per-node transform 1. Thread = (node, o<16), o fixed -> 60 weight
// floats in VGPRs, grid-stride. Output INTERLEAVED g1c1[n*32+2o]=(g,c) float2.
// ---------------------------------------------------------------------------
__global__ __launch_bounds__(256, 4) void k_tf1(
    const float* __restrict__ PQ1,
    const float* __restrict__ x,
    const float* __restrict__ Wg1,   // [10,16]
    const float* __restrict__ We1,   // [3,160]
    const float* __restrict__ be1,   // [160]
    const float* __restrict__ root1, // [10,16]
    const float* __restrict__ bias1, // [16]
    const float* __restrict__ bg1,   // [16]
    float* __restrict__ g1c1)
{
    __shared__ float w[6 * 160 + 32];
    for (int t = threadIdx.x; t < 6 * 160 + 32; t += 256) {
        float v;
        if (t < 960) {
            int slot = t / 160, r = t - slot * 160;
            if (slot == 0)      v = Wg1[r];
            else if (slot <= 3) v = We1[(slot - 1) * 160 + r];
            else if (slot == 4) v = be1[r];
            else                v = root1[r];
        } else if (t < 976) v = bias1[t - 960];
        else                v = bg1[t - 976];
        w[t] = v;
    }
    __syncthreads();
    int o = threadIdx.x & 15;
    int ngrp = threadIdx.x >> 4;         // 0..15
    float wg[10], w0[10], w1[10], w2[10], bm[10], rt[10];
#pragma unroll
    for (int f = 0; f < 10; ++f) {
        wg[f] = w[f * 16 + o];
        w0[f] = w[160 + f * 16 + o];
        w1[f] = w[320 + f * 16 + o];
        w2[f] = w[480 + f * 16 + o];
        bm[f] = w[640 + f * 16 + o];
        rt[f] = w[800 + f * 16 + o];
    }
    float bia = w[960 + o], bgv = w[976 + o];
    for (int node = blockIdx.x * 16 + ngrp; node < N_NODES; node += gridDim.x * 16) {
        const float* P = PQ1 + node * 50;
        const float* xs = x + node * F_INQ;
        float ac = bia, ag = bgv;
#pragma unroll
        for (int f = 0; f < 10; ++f) {
            ac += P[f] * bm[f] + P[10 + f] * w0[f] + P[20 + f] * w1[f]
                + P[30 + f] * w2[f] + xs[f] * rt[f];
            ag += P[40 + f] * wg[f];
        }
        float2 gc;
        gc.x = ag > 0.f ? ag : 0.f;
        gc.y = ac > 0.f ? ac : 0.f;
        *reinterpret_cast<float2*>(g1c1 + node * 32 + 2 * o) = gc;
    }
}

// ---------------------------------------------------------------------------
// K_edge2: weight-free CSR reduction, layer 2. Lane = (node, f<16).
// One float2 load per edge per lane (interleaved g1c1). PQ2[n,80].
// Simple loop, low VGPR, high occupancy (the R7 fusion lesson).
// ---------------------------------------------------------------------------
__global__ __launch_bounds__(256) void k_edge2(
    const float* __restrict__ g1c1,
    const int* __restrict__ rs, const int* __restrict__ bsum,
    const int* __restrict__ ecol, const float4* __restrict__ edata,
    float* __restrict__ PQ2)
{
    int idx = blockIdx.x * 256 + threadIdx.x;   // 3750 blocks exact
    int node = idx >> 4, f = idx & 15;
    int end = rs[node] + bsum[node >> 8];
    int start = (node == 0) ? 0 : (rs[node - 1] + bsum[(node - 1) >> 8]);
    float p0 = 0.f, p1 = 0.f, p2 = 0.f, p3 = 0.f, q = 0.f;
    for (int k = start; k < end; ++k) {
        int col = ecol[k];
        float4 ed = edata[k];
        float2 gc = *reinterpret_cast<const float2*>(g1c1 + col * 32 + 2 * f);
        p0 += gc.y;
        p1 += ed.y * gc.y;
        p2 += ed.z * gc.y;
        p3 += ed.w * gc.y;
        q  += ed.x * gc.x;
    }
    float* P = PQ2 + node * 80;
    P[f]      = p0;
    P[16 + f] = p1;
    P[32 + f] = p2;
    P[48 + f] = p3;
    P[64 + f] = q;
}

// ---------------------------------------------------------------------------
// K_tf2: per-node transform 2. Thread = (node, o<32), o fixed; 96 weight
// floats in VGPRs; grid-stride. c1-self read from interleaved g1c1 (stride 2).
// Output g2c2[n,64] = [g2(32)|c2(32)].
// ---------------------------------------------------------------------------
__global__ __launch_bounds__(256, 3) void k_tf2(
    const float* __restrict__ PQ2,
    const float* __restrict__ g1c1,
    const float* __restrict__ Wg2,   // [16,32]
    const float* __restrict__ We2,   // [3,512]
    const float* __restrict__ be2,   // [512]
    const float* __restrict__ root2, // [16,32]
    const float* __restrict__ bias2, // [32]
    const float* __restrict__ bg2,   // [32]
    float* __restrict__ g2c2)
{
    __shared__ float w[6 * 512 + 64];
    for (int t = threadIdx.x; t < 6 * 512 + 64; t += 256) {
        float v;
        if (t < 3072) {
            int slot = t >> 9, r = t & 511;
            if (slot == 0)      v = Wg2[r];
            else if (slot <= 3) v = We2[(slot - 1) * 512 + r];
            else if (slot == 4) v = be2[r];
            else                v = root2[r];
        } else if (t < 3104) v = bias2[t - 3072];
        else                 v = bg2[t - 3104];
        w[t] = v;
    }
    __syncthreads();
    int o = threadIdx.x & 31;
    int ngrp = threadIdx.x >> 5;         // 0..7
    float wg[16], w0[16], w1[16], w2[16], bm[16], rt[16];
#pragma unroll
    for (int f = 0; f < 16; ++f) {
        wg[f] = w[f * 32 + o];
        w0[f] = w[512 + f * 32 + o];
        w1[f] = w[1024 + f * 32 + o];
        w2[f] = w[1536 + f * 32 + o];
        bm[f] = w[2048 + f * 32 + o];
        rt[f] = w[2560 + f * 32 + o];
    }
    float bia = w[3072 + o], bgv = w[3104 + o];
    for (int node = blockIdx.x * 8 + ngrp; node < N_NODES; node += gridDim.x * 8) {
        const float* P = PQ2 + node * 80;
        const float* cs = g1c1 + node * 32;   // interleaved; c at 2f+1
        float ac = bia, ag = bgv;
#pragma unroll
        for (int f = 0; f < 16; ++f) {
            ac += P[f] * bm[f] + P[16 + f] * w0[f] + P[32 + f] * w1[f]
                + P[48 + f] * w2[f] + cs[2 * f + 1] * rt[f];
            ag += P[64 + f] * wg[f];
        }
        g2c2[node * 64 + o]      = ag > 0.f ? ag : 0.f;
        g2c2[node * 64 + 32 + o] = ac > 0.f ? ac : 0.f;
    }
}

// ---------------------------------------------------------------------------
// K_pool_head: one block per graph; 4 waves stride nodes (lane = channel),
// LDS-reduce, fused MLP head. No atomics.
// ---------------------------------------------------------------------------
__global__ __launch_bounds__(256) void k_pool_head(
    const float* __restrict__ g2c2,
    const int* __restrict__ gs,
    const float* __restrict__ Wd1, const float* __restrict__ bd1,
    const float* __restrict__ Wd2, const float* __restrict__ bd2,
    const float* __restrict__ Wo,  const float* __restrict__ bo,
    float* __restrict__ out)
{
    __shared__ float red[4][64];
    __shared__ float pl[64];
    __shared__ float h1s[16], h2s[8];
    int g = blockIdx.x;
    int s = gs[g], e = gs[g + 1];
    int wv = threadIdx.x >> 6, j = threadIdx.x & 63;
    float acc = 0.f;
    for (int nn = s + wv; nn < e; nn += 4)
        acc += g2c2[nn * 64 + j];
    red[wv][j] = acc;
    __syncthreads();
    if (wv == 0) pl[j] = red[0][j] + red[1][j] + red[2][j] + red[3][j];
    __syncthreads();
    int t = threadIdx.x;
    if (t < 16) {
        float a = bd1[t];
        for (int k = 0; k < 64; ++k) a += pl[k] * Wd1[k * 16 + t];
        h1s[t] = a > 0.f ? a : 0.f;
    }
    __syncthreads();
    if (t < 8) {
        float a = bd2[t];
        for (int k = 0; k < 16; ++k) a += h1s[k] * Wd2[k * 8 + t];
        h2s[t] = a > 0.f ? a : 0.f;
    }
    __syncthreads();
    if (t == 0) {
        float a = bo[0];
        for (int k = 0; k < 8; ++k) a += h2s[k] * Wo[k];
        out[g] = 1.f / (1.f + expf(-a));
    }
}

// ---------------------------------------------------------------------------
// Workspace layout:
//   floats: edata E*float4 | PQ1 N*50 | g1c1 N*32 (interleaved) | PQ2 N*80
//           | g2c2 N*64
//   ints  : rs[N] | cnt[1] | bsum[256] | gs[G+1] | ecol[E]
// 9 dispatches (memset + prep + scan + fill + edge1 + tf1 + edge2 + tf2 + pool).
// ---------------------------------------------------------------------------
extern "C" void kernel_launch(void* const* d_in, const int* in_sizes, int n_in,
                              void* d_out, int out_size, void* d_ws, size_t ws_size,
                              hipStream_t stream)
{
    const float* x      = (const float*)d_in[0];
    const float* a_vals = (const float*)d_in[1];
    const float* efeat  = (const float*)d_in[2];
    const int*   ei     = (const int*)d_in[3];
    const int*   seg    = (const int*)d_in[4];
    const float* Wg1    = (const float*)d_in[5];
    const float* bg1    = (const float*)d_in[6];
    const float* Wg2    = (const float*)d_in[7];
    const float* bg2    = (const float*)d_in[8];
    const float* We1    = (const float*)d_in[9];
    const float* be1    = (const float*)d_in[10];
    const float* root1  = (const float*)d_in[11];
    const float* bias1  = (const float*)d_in[12];
    const float* We2    = (const float*)d_in[13];
    const float* be2    = (const float*)d_in[14];
    const float* root2  = (const float*)d_in[15];
    const float* bias2  = (const float*)d_in[16];
    const float* Wd1    = (const float*)d_in[17];
    const float* bd1    = (const float*)d_in[18];
    const float* Wd2    = (const float*)d_in[19];
    const float* bd2    = (const float*)d_in[20];
    const float* Wo     = (const float*)d_in[21];
    const float* bo     = (const float*)d_in[22];

    float4* edata = (float4*)d_ws;
    float*  PQ1  = (float*)(edata + N_EDGES);
    float*  g1c1 = PQ1 + (size_t)N_NODES * 50;
    float*  PQ2  = g1c1 + (size_t)N_NODES * 32;
    float*  g2c2 = PQ2 + (size_t)N_NODES * 80;
    int*    rs   = (int*)(g2c2 + (size_t)N_NODES * 64);
    int*    cnt  = rs + N_NODES;
    int*    bsum = cnt + 1;
    int*    gs   = bsum + 256;
    int*    ecol = gs + (G_DIM + 1);
    float*  out  = (float*)d_out;

    hipMemsetAsync(rs, 0, sizeof(int) * (N_NODES + 1), stream);  // rs + cnt

    // CSR build + graph segments (3 dispatches)
    k_prep<<<NB_EDGE + NB_SCAN, 256, 0, stream>>>(ei, rs, seg, gs);
    k_scan<<<NB_SCAN, 256, 0, stream>>>(rs, bsum, cnt);
    k_fill<<<NB_EDGE, 256, 0, stream>>>(ei, a_vals, efeat, rs, bsum, ecol, edata);

    // Layer 1
    k_edge1<<<(N_NODES * F_INQ + 255) / 256, 256, 0, stream>>>(
        x, rs, bsum, ecol, edata, PQ1);
    k_tf1  <<<1280, 256, 0, stream>>>(PQ1, x, Wg1, We1, be1, root1, bias1, bg1, g1c1);

    // Layer 2
    k_edge2<<<N_NODES * 16 / 256, 256, 0, stream>>>(g1c1, rs, bsum, ecol, edata, PQ2);
    k_tf2  <<<1280, 256, 0, stream>>>(PQ2, g1c1, Wg2, We2, be2, root2, bias2, bg2, g2c2);

    // Pool + MLP head
    k_pool_head<<<G_DIM, 256, 0, stream>>>(g2c2, gs, Wd1, bd1, Wd2, bd2, Wo, bo, out);
}